// Round 1
// baseline (296.318 us; speedup 1.0000x reference)
//
#include <hip/hip_runtime.h>

typedef __fp16 h2 __attribute__((ext_vector_type(2)));
typedef __fp16 h8 __attribute__((ext_vector_type(8)));
typedef float f4 __attribute__((ext_vector_type(4)));

namespace {
constexpr int JSTR = 72;         // halves per j-row (64 c + 8 pad) -> 144 B, breaks bank aliasing
constexpr int JN = 48;           // j rows; j<4 and j>=36 are permanent zero halo
constexpr int COLH = JN * JSTR;  // 3456 halves = 6912 B per column buffer
}

__global__ __launch_bounds__(256, 4) void corr3d_mfma(
    const float* __restrict__ in1, const float* __restrict__ in2,
    float* __restrict__ out)
{
  __shared__ __align__(16) __fp16 colbuf[2][COLH];  // 13824 B, double-buffered in2 column
  __shared__ __align__(16) float obuf[2 * 9 * 32];  // [pos][dz][d] band reorg, 2304 B

  const int tid = threadIdx.x;
  const int blk = blockIdx.x;  // b(2) x h(32) x wb(16)
  const int b = blk >> 9;
  const int h = (blk >> 4) & 31;
  const int w0 = (blk & 15) << 1;  // two w positions: w0, w0+1

  const int lane = tid & 63;
  const int wv = tid >> 6;  // wave 0..3 = D-tiles (T0,s0),(T1,s0),(T1,s1),(T2,s1)
  const int jb = (wv == 0) ? 0 : (wv == 3) ? 32 : 16;  // A-tile j base
  const int db = (wv >= 2) ? 16 : 0;                   // d-strip base
  const int l15 = lane & 15;
  const int lhi = lane >> 4;

  const float* in1b = in1 + ((size_t)b << 21);
  const float* in2b = in2 + ((size_t)b << 21);

  // zero halo rows of both column buffers (j<4, j>=36): written once, never touched again
  for (int i = tid; i < 1152; i += 256) {
    const int bu = i / 576;
    const int r = i - bu * 576;
    const int jrow = r / 36;
    const int cc = r - jrow * 36;
    const int j = (jrow < 4) ? jrow : jrow + 32;
    h2 z = {(__fp16)0.f, (__fp16)0.f};
    *(h2*)&colbuf[bu][j * JSTR + cc * 2] = z;
  }

  // staging role: d = tid&31 (coalesced), c-quad = tid>>5
  const int sd = tid & 31;
  const int scq = tid >> 5;

  auto stage = [&](const float* src, bool valid, __fp16* dst) {
#pragma unroll
    for (int it = 0; it < 4; ++it) {
      const int cp = scq + (it << 3);  // c-pair 0..31
      h2 v = {(__fp16)0.f, (__fp16)0.f};
      if (valid) {
        const float x = src[((size_t)(2 * cp) << 15) + sd];
        const float y = src[((size_t)(2 * cp + 1) << 15) + sd];
        v = __builtin_amdgcn_cvt_pkrtz(x, y);
      }
      *(h2*)&dst[(4 + sd) * JSTR + 2 * cp] = v;  // [j=4+d][c] layout
    }
  };

  // ---- prologue: load in1 B-operand fragments (per wave: its d-strip, 2 c-halves, 2 pos)
  h8 bfr[2][2];
#pragma unroll
  for (int pos = 0; pos < 2; ++pos) {
    __syncthreads();
    stage(in1b + (h << 10) + ((w0 + pos) << 5), true, colbuf[0]);
    __syncthreads();
#pragma unroll
    for (int ch = 0; ch < 2; ++ch)
      bfr[pos][ch] =
          *(const h8*)&colbuf[0][(4 + db + l15) * JSTR + ch * 32 + (lhi << 3)];
  }
  __syncthreads();
  // stage in2 column 0 into buf 0
  {
    const int hp = h - 4, wp = w0 - 4;
    const bool valid = ((unsigned)hp < 32u) && ((unsigned)wp < 32u);
    stage(in2b + (hp << 10) + (wp << 5), valid, colbuf[0]);
  }
  __syncthreads();

  // band-write targets per (lane, reg): m=(lhi*4+r), n=l15; j=jb+m, d=db+n, dz=j-d
  int boff[4];
  unsigned bmask = 0;
#pragma unroll
  for (int r = 0; r < 4; ++r) {
    const int m = (lhi << 2) + r;
    const int dz = jb + m - db - l15;
    if ((unsigned)dz < 9u) bmask |= 1u << r;
    boff[r] = dz * 32 + db + l15;
  }

  // ---- main loop over 90 columns (hc 0..8, wc 0..9)
  for (int ci = 0; ci < 90; ++ci) {
    if (ci + 1 < 90) {  // stage next column into the other buffer
      const int cn = ci + 1;
      const int hcn = cn / 10;
      const int wcn = cn - hcn * 10;
      const int hp = h - 4 + hcn;
      const int wp = w0 - 4 + wcn;
      const bool valid = ((unsigned)hp < 32u) && ((unsigned)wp < 32u);
      stage(in2b + (hp << 10) + (wp << 5), valid, colbuf[cn & 1]);
    }
    const int hc = ci / 10;
    const int wc = ci - hc * 10;
    const bool serve[2] = {wc <= 8, wc >= 1};  // dx = wc - pos must be in [0,9)

    const __fp16* cb = colbuf[ci & 1];
    const h8 a0 = *(const h8*)&cb[(jb + l15) * JSTR + (lhi << 3)];
    const h8 a1 = *(const h8*)&cb[(jb + l15) * JSTR + 32 + (lhi << 3)];
#pragma unroll
    for (int pos = 0; pos < 2; ++pos) {
      if (serve[pos]) {
        f4 acc = {0.f, 0.f, 0.f, 0.f};
        acc = __builtin_amdgcn_mfma_f32_16x16x32_f16(a0, bfr[pos][0], acc, 0, 0, 0);
        acc = __builtin_amdgcn_mfma_f32_16x16x32_f16(a1, bfr[pos][1], acc, 0, 0, 0);
#pragma unroll
        for (int r = 0; r < 4; ++r)
          if (bmask & (1u << r)) obuf[pos * 288 + boff[r]] = acc[r];
      }
    }
    __syncthreads();  // band writes visible
    // readback [pos][dz][d] rows -> coalesced float4 nontemporal global stores.
    // NT: output is written once and never re-read; without the hint these
    // 191 MB of streaming stores evict the in2 working set (33.5 MB, reused
    // 45x) from L2/L3, which is what the 316 MB FETCH_SIZE was.
    if (tid < 144) {
      const int pos = tid >= 72;
      const int rr = tid - pos * 72;
      const int dz = rr >> 3;
      const int q = rr & 7;
      if (serve[pos]) {
        const f4 v = *(const f4*)&obuf[pos * 288 + dz * 32 + (q << 2)];
        const size_t ch = (size_t)(b * 729 + (hc * 9 + (wc - pos)) * 9 + dz);
        f4* dstp = (f4*)(out + (ch << 15) + (h << 10) + ((w0 + pos) << 5) + (q << 2));
        __builtin_nontemporal_store(v, dstp);
      }
    }
    __syncthreads();  // obuf free for next column's band writes
  }
}

extern "C" void kernel_launch(void* const* d_in, const int* in_sizes, int n_in,
                              void* d_out, int out_size, void* d_ws, size_t ws_size,
                              hipStream_t stream) {
  const float* in1 = (const float*)d_in[0];
  const float* in2 = (const float*)d_in[1];
  float* out = (float*)d_out;
  corr3d_mfma<<<dim3(1024), dim3(256), 0, stream>>>(in1, in2, out);
}

// Round 2
// 280.812 us; speedup vs baseline: 1.0552x; 1.0552x over previous
//
#include <hip/hip_runtime.h>

typedef __fp16 h2 __attribute__((ext_vector_type(2)));
typedef __fp16 h8 __attribute__((ext_vector_type(8)));
typedef float f4 __attribute__((ext_vector_type(4)));

namespace {
constexpr int JSTR = 72;         // halves per j-row (64 c + 8 pad) -> 144 B, breaks bank aliasing
constexpr int JN = 48;           // j rows; j<4 and j>=36 are permanent zero halo
constexpr int COLH = JN * JSTR;  // 3456 halves = 6912 B per column buffer
}

__global__ __launch_bounds__(256, 4) void corr3d_mfma(
    const float* __restrict__ in1, const float* __restrict__ in2,
    float* __restrict__ out)
{
  __shared__ __align__(16) __fp16 colbuf[2][COLH];  // 13824 B, double-buffered in2 column
  __shared__ __align__(16) float obuf[2 * 9 * 32];  // [pos][dz][d] band reorg, 2304 B

  const int tid = threadIdx.x;
  // XCD-aware chunked swizzle (T1): HW round-robins consecutive physical block
  // ids across the 8 non-coherent per-XCD L2s. Blocks sharing in2 columns are
  // CONSECUTIVE logical ids (same h, adjacent wb) -> without the swizzle their
  // shared lines are fetched from HBM by every XCD (~18x fetch amplification,
  // 303 MB observed). Chunked remap gives each XCD one contiguous 128-block
  // slab (b, 8 h-rows, all wb): in2 slice ~4.2 MB ~= L2-resident.
  // 1024 % 8 == 0 -> bijective.
  const int blk = ((blockIdx.x & 7) << 7) | (blockIdx.x >> 3);
  const int b = blk >> 9;
  const int h = (blk >> 4) & 31;
  const int w0 = (blk & 15) << 1;  // two w positions: w0, w0+1

  const int lane = tid & 63;
  const int wv = tid >> 6;  // wave 0..3 = D-tiles (T0,s0),(T1,s0),(T1,s1),(T2,s1)
  const int jb = (wv == 0) ? 0 : (wv == 3) ? 32 : 16;  // A-tile j base
  const int db = (wv >= 2) ? 16 : 0;                   // d-strip base
  const int l15 = lane & 15;
  const int lhi = lane >> 4;

  const float* in1b = in1 + ((size_t)b << 21);
  const float* in2b = in2 + ((size_t)b << 21);

  // zero halo rows of both column buffers (j<4, j>=36): written once, never touched again
  for (int i = tid; i < 1152; i += 256) {
    const int bu = i / 576;
    const int r = i - bu * 576;
    const int jrow = r / 36;
    const int cc = r - jrow * 36;
    const int j = (jrow < 4) ? jrow : jrow + 32;
    h2 z = {(__fp16)0.f, (__fp16)0.f};
    *(h2*)&colbuf[bu][j * JSTR + cc * 2] = z;
  }

  // staging role: d = tid&31 (coalesced), c-quad = tid>>5
  const int sd = tid & 31;
  const int scq = tid >> 5;

  auto stage = [&](const float* src, bool valid, __fp16* dst) {
#pragma unroll
    for (int it = 0; it < 4; ++it) {
      const int cp = scq + (it << 3);  // c-pair 0..31
      h2 v = {(__fp16)0.f, (__fp16)0.f};
      if (valid) {
        const float x = src[((size_t)(2 * cp) << 15) + sd];
        const float y = src[((size_t)(2 * cp + 1) << 15) + sd];
        v = __builtin_amdgcn_cvt_pkrtz(x, y);
      }
      *(h2*)&dst[(4 + sd) * JSTR + 2 * cp] = v;  // [j=4+d][c] layout
    }
  };

  // ---- prologue: load in1 B-operand fragments (per wave: its d-strip, 2 c-halves, 2 pos)
  h8 bfr[2][2];
#pragma unroll
  for (int pos = 0; pos < 2; ++pos) {
    __syncthreads();
    stage(in1b + (h << 10) + ((w0 + pos) << 5), true, colbuf[0]);
    __syncthreads();
#pragma unroll
    for (int ch = 0; ch < 2; ++ch)
      bfr[pos][ch] =
          *(const h8*)&colbuf[0][(4 + db + l15) * JSTR + ch * 32 + (lhi << 3)];
  }
  __syncthreads();
  // stage in2 column 0 into buf 0
  {
    const int hp = h - 4, wp = w0 - 4;
    const bool valid = ((unsigned)hp < 32u) && ((unsigned)wp < 32u);
    stage(in2b + (hp << 10) + (wp << 5), valid, colbuf[0]);
  }
  __syncthreads();

  // band-write targets per (lane, reg): m=(lhi*4+r), n=l15; j=jb+m, d=db+n, dz=j-d
  int boff[4];
  unsigned bmask = 0;
#pragma unroll
  for (int r = 0; r < 4; ++r) {
    const int m = (lhi << 2) + r;
    const int dz = jb + m - db - l15;
    if ((unsigned)dz < 9u) bmask |= 1u << r;
    boff[r] = dz * 32 + db + l15;
  }

  // ---- main loop over 90 columns (hc 0..8, wc 0..9)
  for (int ci = 0; ci < 90; ++ci) {
    if (ci + 1 < 90) {  // stage next column into the other buffer
      const int cn = ci + 1;
      const int hcn = cn / 10;
      const int wcn = cn - hcn * 10;
      const int hp = h - 4 + hcn;
      const int wp = w0 - 4 + wcn;
      const bool valid = ((unsigned)hp < 32u) && ((unsigned)wp < 32u);
      stage(in2b + (hp << 10) + (wp << 5), valid, colbuf[cn & 1]);
    }
    const int hc = ci / 10;
    const int wc = ci - hc * 10;
    const bool serve[2] = {wc <= 8, wc >= 1};  // dx = wc - pos must be in [0,9)

    const __fp16* cb = colbuf[ci & 1];
    const h8 a0 = *(const h8*)&cb[(jb + l15) * JSTR + (lhi << 3)];
    const h8 a1 = *(const h8*)&cb[(jb + l15) * JSTR + 32 + (lhi << 3)];
#pragma unroll
    for (int pos = 0; pos < 2; ++pos) {
      if (serve[pos]) {
        f4 acc = {0.f, 0.f, 0.f, 0.f};
        acc = __builtin_amdgcn_mfma_f32_16x16x32_f16(a0, bfr[pos][0], acc, 0, 0, 0);
        acc = __builtin_amdgcn_mfma_f32_16x16x32_f16(a1, bfr[pos][1], acc, 0, 0, 0);
#pragma unroll
        for (int r = 0; r < 4; ++r)
          if (bmask & (1u << r)) obuf[pos * 288 + boff[r]] = acc[r];
      }
    }
    __syncthreads();  // band writes visible
    // readback [pos][dz][d] rows -> coalesced float4 nontemporal global stores
    if (tid < 144) {
      const int pos = tid >= 72;
      const int rr = tid - pos * 72;
      const int dz = rr >> 3;
      const int q = rr & 7;
      if (serve[pos]) {
        const f4 v = *(const f4*)&obuf[pos * 288 + dz * 32 + (q << 2)];
        const size_t ch = (size_t)(b * 729 + (hc * 9 + (wc - pos)) * 9 + dz);
        f4* dstp = (f4*)(out + (ch << 15) + (h << 10) + ((w0 + pos) << 5) + (q << 2));
        __builtin_nontemporal_store(v, dstp);
      }
    }
    __syncthreads();  // obuf free for next column's band writes
  }
}

extern "C" void kernel_launch(void* const* d_in, const int* in_sizes, int n_in,
                              void* d_out, int out_size, void* d_ws, size_t ws_size,
                              hipStream_t stream) {
  const float* in1 = (const float*)d_in[0];
  const float* in2 = (const float*)d_in[1];
  float* out = (float*)d_out;
  corr3d_mfma<<<dim3(1024), dim3(256), 0, stream>>>(in1, in2, out);
}